// Round 5
// baseline (211.824 us; speedup 1.0000x reference)
//
#include <hip/hip_runtime.h>

#define NQ 12
#define DIM 4096
#define WS 64   // one wave per block, one batch element per wave

// ---------- GF(2)-linear index machinery ----------
__host__ __device__ constexpr int par12(int v) {
    v ^= v >> 8; v ^= v >> 4; v ^= v >> 2; v ^= v >> 1; return v & 1;
}
// CNOT ring permutation (verified in R4: new_state[ringP(i)] = old_state[i]).
__host__ __device__ constexpr int ringP(int i) {
    int r = 0;
    for (int k = 0; k <= 10; ++k) r |= par12((i >> k) & 0xFFF) << k;
    r |= par12(i & 0x7FF) << 11;
    return r;
}
// LDS slot (complex units) for logical index x: row x[11:6], column
// x[5:0] XOR-swizzled by x[9:6] so both row-major and transposed access
// patterns hit distinct bank-pairs within each 16-lane phase.
__device__ __forceinline__ int slotOf(int x) {
    return (x & 0xFC0) | ((x & 63) ^ ((x >> 6) & 15));
}

// Complex 2x2 gate on register pair (r0, r1) with U rows in mlo/mhi.
#define PAIR_OP(r0, r1)                                                   \
    {                                                                     \
        float a0r = ar[r0], a0i = ai[r0], a1r = ar[r1], a1i = ai[r1];     \
        ar[r0] = mlo.x * a0r - mlo.y * a0i + mlo.z * a1r - mlo.w * a1i;   \
        ai[r0] = mlo.x * a0i + mlo.y * a0r + mlo.z * a1i + mlo.w * a1r;   \
        ar[r1] = mhi.x * a0r - mhi.y * a0i + mhi.z * a1r - mhi.w * a1i;   \
        ai[r1] = mhi.x * a0i + mhi.y * a0r + mhi.z * a1i + mhi.w * a1r;   \
    }

__global__ __launch_bounds__(WS, 1) void qsim_kernel(
    const float* __restrict__ x,   // (B, 12) fp32
    const float* __restrict__ w,   // (2, 12, 3) fp32
    float* __restrict__ out)       // (B, 12) fp32
{
    __shared__ float2 sc[DIM];                    // 32 KB wave-private scratch
    __shared__ __align__(16) float fm[2][NQ][8];  // fused U = Rot*RY

    const int L = threadIdx.x;    // lane
    const int b = blockIdx.x;

    // ---- fused gate matrices (single wave: no barrier, lgkmcnt suffices) ----
    if (L < 2 * NQ) {
        int l = L / NQ, q = L % NQ;
        float hy = 0.5f * x[b * NQ + q];
        float cy = cosf(hy), sy = sinf(hy);
        const float* wp = w + (l * NQ + q) * 3;
        float phi = wp[0], the = wp[1], om = wp[2];
        float c = cosf(0.5f * the), s = sinf(0.5f * the);
        float al = 0.5f * (phi + om), be = 0.5f * (phi - om);
        float ca = cosf(al), sa = sinf(al), cb = cosf(be), sb = sinf(be);
        float r00r =  ca * c, r00i = -sa * c;
        float r01r = -cb * s, r01i = -sb * s;
        float r10r =  cb * s, r10i = -sb * s;
        float r11r =  ca * c, r11i =  sa * c;
        float* m = fm[l][q];
        m[0] =  r00r * cy + r01r * sy;  m[1] =  r00i * cy + r01i * sy;  // U00
        m[2] = -r00r * sy + r01r * cy;  m[3] = -r00i * sy + r01i * cy;  // U01
        m[4] =  r10r * cy + r11r * sy;  m[5] =  r10i * cy + r11i * sy;  // U10
        m[6] = -r10r * sy + r11r * cy;  m[7] = -r10i * sy + r11i * cy;  // U11
    }

    // ---- state: P0 layout, amp((L<<6)|r) in regs (ar[r], ai[r]) ----
    float ar[64], ai[64];
#pragma unroll
    for (int r = 0; r < 64; ++r) { ar[r] = 0.f; ai[r] = 0.f; }
    if (L == 0) ar[0] = 1.f;

    const int m15 = L & 15;
    const int pl  = ringP(L);     // lane part of ring permutation (linear)

    for (int l = 0; l < 2; ++l) {
        // ---- stage 1: wires 6..11 = reg bits 5..0 (P0) ----
#pragma unroll
        for (int j = 0; j < 6; ++j) {
            const int q = 11 - j;
            float4 mlo = *(const float4*)&fm[l][q][0];
            float4 mhi = *(const float4*)&fm[l][q][4];
#pragma unroll
            for (int r0 = 0; r0 < 64; ++r0) {
                if (r0 & (1 << j)) continue;
                PAIR_OP(r0, r0 | (1 << j));
            }
        }
        // ---- RT-A: transpose P0 -> P1 (lane bits <-> reg bits) ----
        // write amp i=(L<<6)|r at slotOf(i) = (L<<6)|(r^m15)
#pragma unroll
        for (int r = 0; r < 64; ++r)
            sc[(L << 6) | (r ^ m15)] = make_float2(ar[r], ai[r]);
        // read amp i=(r<<6)|L from slotOf(i) = (r<<6)|(L^(r&15))
#pragma unroll
        for (int r = 0; r < 64; ++r) {
            float2 v = sc[(r << 6) | (L ^ (r & 15))];
            ar[r] = v.x; ai[r] = v.y;
        }
        // ---- stage 2: wires 0..5 = reg bits 5..0 of P1 (bit j <-> wire 5-j) ----
#pragma unroll
        for (int j = 0; j < 6; ++j) {
            const int q = 5 - j;
            float4 mlo = *(const float4*)&fm[l][q][0];
            float4 mhi = *(const float4*)&fm[l][q][4];
#pragma unroll
            for (int r0 = 0; r0 < 64; ++r0) {
                if (r0 & (1 << j)) continue;
                PAIR_OP(r0, r0 | (1 << j));
            }
        }
        // ---- RT-B: CNOT ring fold + back to P0 ----
        // holding amp i=(r<<6)|L: write to slotOf(ringP(i)), ringP linear
#pragma unroll
        for (int r = 0; r < 64; ++r) {
            int xk = ringP(r << 6) ^ pl;       // constant ^ lane part
            sc[slotOf(xk)] = make_float2(ar[r], ai[r]);
        }
        // read amp j=(L<<6)|r from slotOf(j)
#pragma unroll
        for (int r = 0; r < 64; ++r) {
            float2 v = sc[(L << 6) | (r ^ m15)];
            ar[r] = v.x; ai[r] = v.y;
        }
    }

    // ---- epilogue: <Z_q>, P0 layout ----
    float tot = 0.f, z0 = 0.f, z1 = 0.f, z2 = 0.f, z3 = 0.f, z4 = 0.f, z5 = 0.f;
#pragma unroll
    for (int r = 0; r < 64; ++r) {
        float p = ar[r] * ar[r] + ai[r] * ai[r];
        tot += p;
        z0 += (r & 1)  ? -p : p;   // bit0 -> wire 11
        z1 += (r & 2)  ? -p : p;   // wire 10
        z2 += (r & 4)  ? -p : p;   // wire 9
        z3 += (r & 8)  ? -p : p;   // wire 8
        z4 += (r & 16) ? -p : p;   // wire 7
        z5 += (r & 32) ? -p : p;   // wire 6
    }
    float v[NQ];
#pragma unroll
    for (int q = 0; q < 6; ++q)            // wire q <- lane bit (5-q)
        v[q] = ((L >> (5 - q)) & 1) ? -tot : tot;
    v[6] = z5; v[7] = z4; v[8] = z3; v[9] = z2; v[10] = z1; v[11] = z0;

#pragma unroll
    for (int q = 0; q < NQ; ++q)
        for (int off = 32; off > 0; off >>= 1)
            v[q] += __shfl_xor(v[q], off, 64);

    if (L == 0) {
        float4* o = (float4*)(out + b * NQ);
        o[0] = make_float4(v[0], v[1], v[2], v[3]);
        o[1] = make_float4(v[4], v[5], v[6], v[7]);
        o[2] = make_float4(v[8], v[9], v[10], v[11]);
    }
}

extern "C" void kernel_launch(void* const* d_in, const int* in_sizes, int n_in,
                              void* d_out, int out_size, void* d_ws, size_t ws_size,
                              hipStream_t stream) {
    int xi = 0, wi = 1;
    if (n_in >= 2 && in_sizes[1] > in_sizes[0]) { xi = 1; wi = 0; }
    const float* x = (const float*)d_in[xi];
    const float* w = (const float*)d_in[wi];
    float* out = (float*)d_out;
    const int B = in_sizes[xi] / NQ;   // 1024
    qsim_kernel<<<B, WS, 0, stream>>>(x, w, out);
}

// Round 6
// 82.235 us; speedup vs baseline: 2.5758x; 2.5758x over previous
//
#include <hip/hip_runtime.h>

#define NQ 12
#define DIM 4096
#define NT 128   // 2 waves per block; one batch element per block

typedef float v2 __attribute__((ext_vector_type(2)));

// ---------- GF(2)-linear index machinery ----------
__host__ __device__ constexpr int par12(int v) {
    v ^= v >> 8; v ^= v >> 4; v ^= v >> 2; v ^= v >> 1; return v & 1;
}
// CNOT ring permutation (verified R4/R5: new_state[ringP(i)] = old_state[i]).
__host__ __device__ constexpr int ringP(int i) {
    int r = 0;
    for (int k = 0; k <= 10; ++k) r |= par12((i >> k) & 0xFFF) << k;
    r |= par12(i & 0x7FF) << 11;
    return r;
}
// Inverse: x_k = y_k^y_{k+1} (k<=9); x10 = y11^y0^y10; x11 = y0^y11.
__host__ __device__ constexpr int ringInv(int y) {
    int x = 0;
    for (int k = 0; k <= 9; ++k) x |= (((y >> k) ^ (y >> (k + 1))) & 1) << k;
    x |= (((y >> 11) ^ y ^ (y >> 10)) & 1) << 10;
    x |= ((y ^ (y >> 11)) & 1) << 11;
    return x;
}
static_assert(ringInv(ringP(0x800)) == 0x800, "");
static_assert(ringInv(ringP(0x001)) == 0x001, "");
static_assert(ringInv(ringP(0xABC)) == 0xABC, "");
static_assert(ringInv(ringP(0x555)) == 0x555, "");
// LDS slot (float2 units). Linear: SL(a^b)=SL(a)^SL(b); preserves bit 11.
__host__ __device__ constexpr int SL(int i) { return i ^ ((i >> 5) & 31); }

// acc += c * a (complex, packed): c.x*a + c.y*(-a.y, a.x)
__device__ __forceinline__ v2 cmadd(v2 c, v2 a, v2 acc) {
    acc += c.x * a;
    v2 j; j.x = -a.y; j.y = a.x;
    acc += c.y * j;
    return acc;
}
// 2x2 complex gate on amp pair
__device__ __forceinline__ void gate2(v2& A0, v2& A1, v2 u00, v2 u01, v2 u10, v2 u11) {
    v2 n0 = cmadd(u01, A1, cmadd(u00, A0, (v2){0.f, 0.f}));
    v2 n1 = cmadd(u11, A1, cmadd(u10, A0, (v2){0.f, 0.f}));
    A0 = n0; A1 = n1;
}

__global__ __launch_bounds__(NT, 2) void qsim_kernel(
    const float* __restrict__ x,   // (B, 12) fp32
    const float* __restrict__ w,   // (2, 12, 3) fp32
    float* __restrict__ out)       // (B, 12) fp32
{
    __shared__ v2 sc[DIM];                        // 32 KB state scratch (re,im)
    __shared__ __align__(16) float fm[2][NQ][8];  // fused U = Rot*RY
    __shared__ float red[2][NQ];

    const int t = threadIdx.x;
    const int L = t & 63;
    const int W = t >> 6;
    const int b = blockIdx.x;

    // ---- fused gate matrices U = Rot(phi,theta,omega) * RY(x_q) ----
    if (t < 2 * NQ) {
        int l = t / NQ, q = t % NQ;
        float hy = 0.5f * x[b * NQ + q];
        float cy = cosf(hy), sy = sinf(hy);
        const float* wp = w + (l * NQ + q) * 3;
        float phi = wp[0], the = wp[1], om = wp[2];
        float c = cosf(0.5f * the), s = sinf(0.5f * the);
        float al = 0.5f * (phi + om), be = 0.5f * (phi - om);
        float ca = cosf(al), sa = sinf(al), cb = cosf(be), sb = sinf(be);
        float r00r =  ca * c, r00i = -sa * c;
        float r01r = -cb * s, r01i = -sb * s;
        float r10r =  cb * s, r10i = -sb * s;
        float r11r =  ca * c, r11i =  sa * c;
        float* m = fm[l][q];
        m[0] =  r00r * cy + r01r * sy;  m[1] =  r00i * cy + r01i * sy;  // U00
        m[2] = -r00r * sy + r01r * cy;  m[3] = -r00i * sy + r01i * cy;  // U01
        m[4] =  r10r * cy + r11r * sy;  m[5] =  r10i * cy + r11i * sy;  // U10
        m[6] = -r10r * sy + r11r * cy;  m[7] = -r10i * sy + r11i * cy;  // U11
    }
    __syncthreads();

    // ---- state P0: amp((W<<11)|(L<<5)|r) in A[r], r in [0,32) ----
    v2 A[32];
#pragma unroll
    for (int r = 0; r < 32; ++r) A[r] = (v2){0.f, 0.f};
    if (t == 0) A[0].x = 1.f;

    // per-thread slot constants
    const int sT0 = SL((W << 11) | (L << 5));              // P0: slot = sT0 ^ r
    const int sT1 = SL((W << 11) | L);                     // P1: slot = sT1 ^ SL(r'<<6)
    const int baseWL = ringInv((W << 11) | (L << 5)) & 0x7FF;
    const int slotBase = SL(baseWL);                       // fold: slot0 = slotBase ^ SL(ringInv(r)&0x7FF)

    for (int l = 0; l < 2; ++l) {
        // ---- stage A: wires 11..7 = reg bits 0..4 ----
#pragma unroll
        for (int j = 0; j < 5; ++j) {
            const int q = 11 - j;
            v2 u00 = *(const v2*)&fm[l][q][0], u01 = *(const v2*)&fm[l][q][2];
            v2 u10 = *(const v2*)&fm[l][q][4], u11 = *(const v2*)&fm[l][q][6];
#pragma unroll
            for (int r0 = 0; r0 < 32; ++r0) {
                if (r0 & (1 << j)) continue;
                gate2(A[r0], A[r0 | (1 << j)], u00, u01, u10, u11);
            }
        }
        // ---- wire 6 = lane bit 0: shfl-xor(1) butterfly ----
        {
            v2 u00 = *(const v2*)&fm[l][6][0], u01 = *(const v2*)&fm[l][6][2];
            v2 u10 = *(const v2*)&fm[l][6][4], u11 = *(const v2*)&fm[l][6][6];
            const int b5 = L & 1;
            v2 cs, cp;
            cs.x = b5 ? u11.x : u00.x;  cs.y = b5 ? u11.y : u00.y;
            cp.x = b5 ? u10.x : u01.x;  cp.y = b5 ? u10.y : u01.y;
#pragma unroll
            for (int r = 0; r < 32; ++r) {
                v2 P;
                P.x = __shfl_xor(A[r].x, 1, 64);
                P.y = __shfl_xor(A[r].y, 1, 64);
                A[r] = cmadd(cp, P, cmadd(cs, A[r], (v2){0.f, 0.f}));
            }
        }
        // ---- RT1 (wave-private, no barrier): P0 -> P1 ----
#pragma unroll
        for (int r = 0; r < 32; ++r) sc[sT0 ^ r] = A[r];
#pragma unroll
        for (int r = 0; r < 32; ++r)
            A[r] = sc[sT1 ^ ((r << 6) ^ ((r & 15) << 1))];   // SL(r<<6)
        // ---- stage B: wires 5..1 = P1 reg bits 0..4 ----
#pragma unroll
        for (int j = 0; j < 5; ++j) {
            const int q = 5 - j;
            v2 u00 = *(const v2*)&fm[l][q][0], u01 = *(const v2*)&fm[l][q][2];
            v2 u10 = *(const v2*)&fm[l][q][4], u11 = *(const v2*)&fm[l][q][6];
#pragma unroll
            for (int r0 = 0; r0 < 32; ++r0) {
                if (r0 & (1 << j)) continue;
                gate2(A[r0], A[r0 | (1 << j)], u00, u01, u10, u11);
            }
        }
        // ---- RT2: write P1 back, then fold wire 0 + CNOT ring on read ----
#pragma unroll
        for (int r = 0; r < 32; ++r)
            sc[sT1 ^ ((r << 6) ^ ((r & 15) << 1))] = A[r];
        __syncthreads();
        {
            v2 u00 = *(const v2*)&fm[l][0][0], u01 = *(const v2*)&fm[l][0][2];
            v2 u10 = *(const v2*)&fm[l][0][4], u11 = *(const v2*)&fm[l][0][6];
            // b11 = (r&1)^W selects the U row
            v2 cE0, cE1, cO0, cO1;
            cE0 = W ? u10 : u00;  cE1 = W ? u11 : u01;   // even r
            cO0 = W ? u00 : u10;  cO1 = W ? u01 : u11;   // odd r
#pragma unroll
            for (int r = 0; r < 32; ++r) {
                const int slot0 = slotBase ^ SL(ringInv(r) & 0x7FF);
                v2 s0 = sc[slot0];
                v2 s1 = sc[slot0 | 0x800];
                v2 c0 = (r & 1) ? cO0 : cE0;
                v2 c1 = (r & 1) ? cO1 : cE1;
                A[r] = cmadd(c1, s1, cmadd(c0, s0, (v2){0.f, 0.f}));
            }
        }
        __syncthreads();   // all fold-reads done before next layer's RT1 writes
    }

    // ---- epilogue: <Z_q> ----
    float tot = 0.f, z7 = 0.f, z8 = 0.f, z9 = 0.f, z10 = 0.f, z11 = 0.f;
#pragma unroll
    for (int r = 0; r < 32; ++r) {
        float p = A[r].x * A[r].x + A[r].y * A[r].y;
        tot += p;
        z7  += (r & 16) ? -p : p;   // wire 7  <- bit 4
        z8  += (r & 8)  ? -p : p;   // wire 8  <- bit 3
        z9  += (r & 4)  ? -p : p;   // wire 9  <- bit 2
        z10 += (r & 2)  ? -p : p;   // wire 10 <- bit 1
        z11 += (r & 1)  ? -p : p;   // wire 11 <- bit 0
    }
    float v[NQ];
    v[0] = W ? -tot : tot;
#pragma unroll
    for (int q = 1; q <= 6; ++q)              // wire q <- lane bit (6-q)
        v[q] = ((L >> (6 - q)) & 1) ? -tot : tot;
    v[7] = z7; v[8] = z8; v[9] = z9; v[10] = z10; v[11] = z11;

#pragma unroll
    for (int q = 0; q < NQ; ++q)
        for (int off = 32; off > 0; off >>= 1)
            v[q] += __shfl_xor(v[q], off, 64);

    if (L == 0) {
#pragma unroll
        for (int q = 0; q < NQ; ++q) red[W][q] = v[q];
    }
    __syncthreads();
    if (t < NQ) out[b * NQ + t] = red[0][t] + red[1][t];
}

extern "C" void kernel_launch(void* const* d_in, const int* in_sizes, int n_in,
                              void* d_out, int out_size, void* d_ws, size_t ws_size,
                              hipStream_t stream) {
    int xi = 0, wi = 1;
    if (n_in >= 2 && in_sizes[1] > in_sizes[0]) { xi = 1; wi = 0; }
    const float* x = (const float*)d_in[xi];
    const float* w = (const float*)d_in[wi];
    float* out = (float*)d_out;
    const int B = in_sizes[xi] / NQ;   // 1024
    qsim_kernel<<<B, NT, 0, stream>>>(x, w, out);
}

// Round 7
// 70.768 us; speedup vs baseline: 2.9932x; 1.1620x over previous
//
#include <hip/hip_runtime.h>

#define NQ 12
#define DIM 4096
#define NT 128   // 2 waves per block; one batch element per block

typedef float v2 __attribute__((ext_vector_type(2)));

// ---------- GF(2)-linear index machinery (HW-verified R4/R6) ----------
__host__ __device__ constexpr int par12(int v) {
    v ^= v >> 8; v ^= v >> 4; v ^= v >> 2; v ^= v >> 1; return v & 1;
}
// CNOT ring permutation: new_state[ringP(i)] = old_state[i].
__host__ __device__ constexpr int ringP(int i) {
    int r = 0;
    for (int k = 0; k <= 10; ++k) r |= par12((i >> k) & 0xFFF) << k;
    r |= par12(i & 0x7FF) << 11;
    return r;
}
__host__ __device__ constexpr int ringInv(int y) {
    int x = 0;
    for (int k = 0; k <= 9; ++k) x |= (((y >> k) ^ (y >> (k + 1))) & 1) << k;
    x |= (((y >> 11) ^ y ^ (y >> 10)) & 1) << 10;
    x |= ((y ^ (y >> 11)) & 1) << 11;
    return x;
}
static_assert(ringInv(ringP(0x800)) == 0x800, "");
static_assert(ringInv(ringP(0xABC)) == 0xABC, "");
// LDS slot (float2 units). Linear; preserves bit 11 (wave half).
__host__ __device__ constexpr int SL(int i) { return i ^ ((i >> 5) & 31); }

// acc += c * a (complex):
__device__ __forceinline__ v2 cmadd(v2 c, v2 a, v2 acc) {
    acc += c.x * a;
    v2 j; j.x = -a.y; j.y = a.x;
    acc += c.y * j;
    return acc;
}
__device__ __forceinline__ v2 cmul(v2 c, v2 a) { return cmadd(c, a, (v2){0.f, 0.f}); }
__device__ __forceinline__ void gate2(v2& A0, v2& A1, v2 u00, v2 u01, v2 u10, v2 u11) {
    v2 n0 = cmadd(u01, A1, cmul(u00, A0));
    v2 n1 = cmadd(u11, A1, cmul(u10, A0));
    A0 = n0; A1 = n1;
}

__global__ __launch_bounds__(NT, 2) void qsim_kernel(
    const float* __restrict__ x,   // (B, 12) fp32
    const float* __restrict__ w,   // (2, 12, 3) fp32
    float* __restrict__ out)       // (B, 12) fp32
{
    __shared__ v2 sc[DIM];                        // 32 KB state scratch
    __shared__ __align__(16) float fm[2][NQ][8];  // fused U = Rot*RY
    __shared__ float red[2][NQ];

    const int t = threadIdx.x;
    const int L = t & 63;
    const int W = t >> 6;
    const int b = blockIdx.x;

    // ---- fused gate matrices U = Rot(phi,theta,omega) * RY(x_q) ----
    if (t < 2 * NQ) {
        int l = t / NQ, q = t % NQ;
        float hy = 0.5f * x[b * NQ + q];
        float cy = cosf(hy), sy = sinf(hy);
        const float* wp = w + (l * NQ + q) * 3;
        float phi = wp[0], the = wp[1], om = wp[2];
        float c = cosf(0.5f * the), s = sinf(0.5f * the);
        float al = 0.5f * (phi + om), be = 0.5f * (phi - om);
        float ca = cosf(al), sa = sinf(al), cb = cosf(be), sb = sinf(be);
        float r00r =  ca * c, r00i = -sa * c;
        float r01r = -cb * s, r01i = -sb * s;
        float r10r =  cb * s, r10i = -sb * s;
        float r11r =  ca * c, r11i =  sa * c;
        float* m = fm[l][q];
        m[0] =  r00r * cy + r01r * sy;  m[1] =  r00i * cy + r01i * sy;  // U00
        m[2] = -r00r * sy + r01r * cy;  m[3] = -r00i * sy + r01i * cy;  // U01
        m[4] =  r10r * cy + r11r * sy;  m[5] =  r10i * cy + r11i * sy;  // U10
        m[6] = -r10r * sy + r11r * cy;  m[7] = -r10i * sy + r11i * cy;  // U11
    }
    __syncthreads();

    // ---- layer 1 pre-ring is a product state: amp(i) = prod_q v_q[i_q],
    //      v_q = column 0 of fm[0][q]. Build P0 amps by doubling tree. ----
    // P0: i = (W<<11)|(L<<5)|r. Lane-const part: wire 0 <- W; wires 1..6 <- L bits 5..0.
    v2 A[32];
    {
        v2 cl = *(const v2*)&fm[0][0][W ? 4 : 0];          // v_0[W]
#pragma unroll
        for (int q = 1; q <= 6; ++q) {
            int bit = (L >> (6 - q)) & 1;
            cl = cmul(cl, *(const v2*)&fm[0][q][bit ? 4 : 0]);
        }
        A[0] = cl;
#pragma unroll
        for (int k = 0; k < 5; ++k) {                      // r bit k <- wire 11-k
            v2 v0 = *(const v2*)&fm[0][11 - k][0];
            v2 v1 = *(const v2*)&fm[0][11 - k][4];
#pragma unroll
            for (int m = 0; m < (1 << k); ++m) {
                A[m | (1 << k)] = cmul(A[m], v1);
                A[m] = cmul(A[m], v0);
            }
        }
    }

    // ---- ring 1: LDS permutation round-trip (verified ringInv fold) ----
    const int sT0 = SL((W << 11) | (L << 5));              // P0 slot = sT0 ^ r (r<32)
#pragma unroll
    for (int r = 0; r < 32; ++r) sc[sT0 ^ r] = A[r];
    __syncthreads();
    {
        const int sRB = SL(ringInv((W << 11) | (L << 5)));
#pragma unroll
        for (int r = 0; r < 32; ++r)
            A[r] = sc[sRB ^ SL(ringInv(r))];               // amp_before(ringInv(i))
    }
    __syncthreads();   // all ring-reads done before RT1 writes below

    // ---- layer 2 (l=1): 12 fused 1q gates ----
    // stage A: wires 11..7 = P0 reg bits 0..4
#pragma unroll
    for (int j = 0; j < 5; ++j) {
        const int q = 11 - j;
        v2 u00 = *(const v2*)&fm[1][q][0], u01 = *(const v2*)&fm[1][q][2];
        v2 u10 = *(const v2*)&fm[1][q][4], u11 = *(const v2*)&fm[1][q][6];
#pragma unroll
        for (int r0 = 0; r0 < 32; ++r0) {
            if (r0 & (1 << j)) continue;
            gate2(A[r0], A[r0 | (1 << j)], u00, u01, u10, u11);
        }
    }
    // wire 6 = lane bit 0: shfl-xor(1) butterfly
    {
        v2 u00 = *(const v2*)&fm[1][6][0], u01 = *(const v2*)&fm[1][6][2];
        v2 u10 = *(const v2*)&fm[1][6][4], u11 = *(const v2*)&fm[1][6][6];
        const int b5 = L & 1;
        v2 cs, cp;
        cs.x = b5 ? u11.x : u00.x;  cs.y = b5 ? u11.y : u00.y;
        cp.x = b5 ? u10.x : u01.x;  cp.y = b5 ? u10.y : u01.y;
#pragma unroll
        for (int r = 0; r < 32; ++r) {
            v2 P;
            P.x = __shfl_xor(A[r].x, 1, 64);
            P.y = __shfl_xor(A[r].y, 1, 64);
            A[r] = cmadd(cp, P, cmul(cs, A[r]));
        }
    }
    // RT1 (wave-private, no barrier): P0 -> P1, A[r] = amp((W<<11)|(r<<6)|L)
    const int sT1 = SL((W << 11) | L);
#pragma unroll
    for (int r = 0; r < 32; ++r) sc[sT0 ^ r] = A[r];
#pragma unroll
    for (int r = 0; r < 32; ++r)
        A[r] = sc[sT1 ^ ((r << 6) ^ ((r & 15) << 1))];     // SL(r<<6)
    // stage B: wires 5..1 = P1 reg bits 0..4
#pragma unroll
    for (int j = 0; j < 5; ++j) {
        const int q = 5 - j;
        v2 u00 = *(const v2*)&fm[1][q][0], u01 = *(const v2*)&fm[1][q][2];
        v2 u10 = *(const v2*)&fm[1][q][4], u11 = *(const v2*)&fm[1][q][6];
#pragma unroll
        for (int r0 = 0; r0 < 32; ++r0) {
            if (r0 & (1 << j)) continue;
            gate2(A[r0], A[r0 | (1 << j)], u00, u01, u10, u11);
        }
    }
    // wire 0 = bit 11 = W: cross-wave exchange via LDS, stay in P1
    {
#pragma unroll
        for (int r = 0; r < 32; ++r)
            sc[sT1 ^ ((r << 6) ^ ((r & 15) << 1))] = A[r];
        __syncthreads();
        v2 u00 = *(const v2*)&fm[1][0][0], u01 = *(const v2*)&fm[1][0][2];
        v2 u10 = *(const v2*)&fm[1][0][4], u11 = *(const v2*)&fm[1][0][6];
        v2 cs, cp;
        cs.x = W ? u11.x : u00.x;  cs.y = W ? u11.y : u00.y;
        cp.x = W ? u10.x : u01.x;  cp.y = W ? u10.y : u01.y;
#pragma unroll
        for (int r = 0; r < 32; ++r) {
            v2 P = sc[(sT1 ^ 0x800) ^ ((r << 6) ^ ((r & 15) << 1))];
            A[r] = cmadd(cp, P, cmul(cs, A[r]));
        }
    }

    // ---- epilogue: ring 2 folded into sign masks (bit_m(ringP) parities).
    // P1: i = (W<<11)|(r<<6)|L. <Z_q> sign = parity(i & T_q), T_{11-q}:
    //   q=0: L all ^ r all;  q=1..5: r-mask {0x10,0x18,0x1C,0x1E,0x1F} ^ W;
    //   q=6..11: r all ^ W ^ L-mask {0x20,0x30,0x38,0x3C,0x3E,0x3F}. ----
    float a1 = 0.f, a2 = 0.f, a3 = 0.f, a4 = 0.f, aF = 0.f;
#pragma unroll
    for (int r = 0; r < 32; ++r) {
        float p = A[r].x * A[r].x + A[r].y * A[r].y;
        a1 += par12(r & 0x10) ? -p : p;
        a2 += par12(r & 0x18) ? -p : p;
        a3 += par12(r & 0x1C) ? -p : p;
        a4 += par12(r & 0x1E) ? -p : p;
        aF += par12(r & 0x1F) ? -p : p;
    }
    float v[NQ];
    v[0] = (__popc(L & 0x3F) & 1) ? -aF : aF;
    v[1] = W ? -a1 : a1;
    v[2] = W ? -a2 : a2;
    v[3] = W ? -a3 : a3;
    v[4] = W ? -a4 : a4;
    v[5] = W ? -aF : aF;
#pragma unroll
    for (int q = 6; q < NQ; ++q) {
        int mask = 0x40 - (1 << (11 - q));          // L bits (11-q)..5
        int s = W ^ (__popc(L & mask) & 1);
        v[q] = s ? -aF : aF;
    }

#pragma unroll
    for (int q = 0; q < NQ; ++q)
        for (int off = 32; off > 0; off >>= 1)
            v[q] += __shfl_xor(v[q], off, 64);

    if (L == 0) {
#pragma unroll
        for (int q = 0; q < NQ; ++q) red[W][q] = v[q];
    }
    __syncthreads();
    if (t < NQ) out[b * NQ + t] = red[0][t] + red[1][t];
}

extern "C" void kernel_launch(void* const* d_in, const int* in_sizes, int n_in,
                              void* d_out, int out_size, void* d_ws, size_t ws_size,
                              hipStream_t stream) {
    int xi = 0, wi = 1;
    if (n_in >= 2 && in_sizes[1] > in_sizes[0]) { xi = 1; wi = 0; }
    const float* x = (const float*)d_in[xi];
    const float* w = (const float*)d_in[wi];
    float* out = (float*)d_out;
    const int B = in_sizes[xi] / NQ;   // 1024
    qsim_kernel<<<B, NT, 0, stream>>>(x, w, out);
}

// Round 8
// 69.877 us; speedup vs baseline: 3.0314x; 1.0127x over previous
//
#include <hip/hip_runtime.h>

#define NQ 12
#define NT 256   // 4 waves per block; one batch element per block; 16 amps/thread

typedef float v2 __attribute__((ext_vector_type(2)));

// ---------- GF(2)-linear index machinery (HW-verified R4/R6/R7) ----------
__host__ __device__ constexpr int par12(int v) {
    v ^= v >> 8; v ^= v >> 4; v ^= v >> 2; v ^= v >> 1; return v & 1;
}
// CNOT ring permutation: new_state[ringP(i)] = old_state[i].
__host__ __device__ constexpr int ringP(int i) {
    int r = 0;
    for (int k = 0; k <= 10; ++k) r |= par12((i >> k) & 0xFFF) << k;
    r |= par12(i & 0x7FF) << 11;
    return r;
}
// LDS slot swizzle (linear, modifies low5 only): all six access patterns are
// 2-lanes-per-bank-pair (free) under this, incl. the SL(ringP(g)) tree-write.
__host__ __device__ constexpr int SL(int i) { return i ^ ((i >> 5) & 31); }

__device__ __forceinline__ v2 cmadd(v2 c, v2 a, v2 acc) {
    acc += c.x * a;
    v2 j; j.x = -a.y; j.y = a.x;
    acc += c.y * j;
    return acc;
}
__device__ __forceinline__ v2 cmul(v2 c, v2 a) { return cmadd(c, a, (v2){0.f, 0.f}); }
__device__ __forceinline__ void gate2(v2& A0, v2& A1, v2 u00, v2 u01, v2 u10, v2 u11) {
    v2 n0 = cmadd(u01, A1, cmul(u00, A0));
    v2 n1 = cmadd(u11, A1, cmul(u10, A0));
    A0 = n0; A1 = n1;
}

__global__ __launch_bounds__(NT, 4) void qsim_kernel(
    const float* __restrict__ x,   // (B, 12) fp32
    const float* __restrict__ w,   // (2, 12, 3) fp32
    float* __restrict__ out)       // (B, 12) fp32
{
    __shared__ v2 sc[4096];                       // 32 KB state scratch
    __shared__ __align__(16) float fm[2][NQ][8];  // fused U = Rot*RY
    __shared__ float red[4][NQ];

    const int t  = threadIdx.x;
    const int L  = t & 63;
    const int Wv = t >> 6;        // wave id 0..3
    const int b  = blockIdx.x;

    // ---- fused gate matrices U = Rot(phi,theta,omega) * RY(x_q) ----
    if (t < 2 * NQ) {
        int l = t / NQ, q = t % NQ;
        float hy = 0.5f * x[b * NQ + q];
        float cy = cosf(hy), sy = sinf(hy);
        const float* wp = w + (l * NQ + q) * 3;
        float phi = wp[0], the = wp[1], om = wp[2];
        float c = cosf(0.5f * the), s = sinf(0.5f * the);
        float al = 0.5f * (phi + om), be = 0.5f * (phi - om);
        float ca = cosf(al), sa = sinf(al), cb = cosf(be), sb = sinf(be);
        float r00r =  ca * c, r00i = -sa * c;
        float r01r = -cb * s, r01i = -sb * s;
        float r10r =  cb * s, r10i = -sb * s;
        float r11r =  ca * c, r11i =  sa * c;
        float* m = fm[l][q];
        m[0] =  r00r * cy + r01r * sy;  m[1] =  r00i * cy + r01i * sy;  // U00
        m[2] = -r00r * sy + r01r * cy;  m[3] = -r00i * sy + r01i * cy;  // U01
        m[4] =  r10r * cy + r11r * sy;  m[5] =  r10i * cy + r11i * sy;  // U10
        m[6] = -r10r * sy + r11r * cy;  m[7] = -r10i * sy + r11i * cy;  // U11
    }

    // ---- per-thread slot bases ----
    // Q0: i = (Wv<<10)|(L<<4)|r   (reg bits -> wires 11..8)
    // Q1: i = (Wv<<10)|(L54<<8)|(r<<4)|L30   (reg bits -> wires 7..4)
    // Q2: i = (r<<8)|(Wv<<6)|L    (reg bits -> wires 3..0)
    const int g0    = (Wv << 10) | (L << 4);
    const int rbase = SL(g0);
    const int wbase = SL(ringP(g0));                       // ring1 fold base
    const int q1i   = (Wv << 10) | ((L >> 4) << 8) | (L & 15);
    const int q1b   = SL(q1i);
    const int q2t   = (Wv << 6) | L;
    const int q2b   = q2t ^ ((q2t >> 5) & 31);

    __syncthreads();   // fm ready  [barrier 1]

    // ---- layer-1 product state, built directly in registers ----
    // g = (Wv<<10)|(L<<4)|r: wire0<-Wv1, wire1<-Wv0, wire(2..7)<-L bit(5..0), wire(11-j)<-r bit j
    v2 A[16];
    {
        v2 cl = *(const v2*)&fm[0][0][(Wv >> 1) ? 4 : 0];
        cl = cmul(*(const v2*)&fm[0][1][(Wv & 1) ? 4 : 0], cl);
#pragma unroll
        for (int wq = 2; wq <= 7; ++wq)
            cl = cmul(*(const v2*)&fm[0][wq][((L >> (7 - wq)) & 1) ? 4 : 0], cl);
        A[0] = cl;
#pragma unroll
        for (int j = 0; j < 4; ++j) {
            v2 c0 = *(const v2*)&fm[0][11 - j][0];
            v2 c1 = *(const v2*)&fm[0][11 - j][4];
#pragma unroll
            for (int m = 0; m < (1 << j); ++m) {
                A[m | (1 << j)] = cmul(c1, A[m]);
                A[m] = cmul(c0, A[m]);
            }
        }
    }

    // ---- tree-write at slot SL(ringP(g)): ring1 folded into addressing ----
#pragma unroll
    for (int r = 0; r < 16; ++r) sc[wbase ^ ringP(r)] = A[r];
    __syncthreads();   // [barrier 2]
    // post-ring state, Q0 layout: trivial read pattern
#pragma unroll
    for (int r = 0; r < 16; ++r) A[r] = sc[rbase ^ r];

    // ---- gates wires 11..8 (Q0 reg bit j <-> wire 11-j) ----
#pragma unroll
    for (int j = 0; j < 4; ++j) {
        const int q = 11 - j;
        float4 lo = *(const float4*)&fm[1][q][0], hi = *(const float4*)&fm[1][q][4];
        v2 u00 = {lo.x, lo.y}, u01 = {lo.z, lo.w}, u10 = {hi.x, hi.y}, u11 = {hi.z, hi.w};
#pragma unroll
        for (int r0 = 0; r0 < 16; ++r0) {
            if (r0 & (1 << j)) continue;
            gate2(A[r0], A[r0 | (1 << j)], u00, u01, u10, u11);
        }
    }

    // ---- T1: Q0 -> Q1 (slots are per-lane private across phases: no barrier) ----
#pragma unroll
    for (int r = 0; r < 16; ++r) sc[rbase ^ r] = A[r];
#pragma unroll
    for (int r = 0; r < 16; ++r) A[r] = sc[q1b ^ ((r << 4) ^ (r >> 1))];

    // ---- gates wires 7..4 (Q1 reg bit j <-> wire 7-j) ----
#pragma unroll
    for (int j = 0; j < 4; ++j) {
        const int q = 7 - j;
        float4 lo = *(const float4*)&fm[1][q][0], hi = *(const float4*)&fm[1][q][4];
        v2 u00 = {lo.x, lo.y}, u01 = {lo.z, lo.w}, u10 = {hi.x, hi.y}, u11 = {hi.z, hi.w};
#pragma unroll
        for (int r0 = 0; r0 < 16; ++r0) {
            if (r0 & (1 << j)) continue;
            gate2(A[r0], A[r0 | (1 << j)], u00, u01, u10, u11);
        }
    }

    // ---- T2: Q1 -> Q2 (cross-wave: barrier between write and read) ----
#pragma unroll
    for (int r = 0; r < 16; ++r) sc[q1b ^ ((r << 4) ^ (r >> 1))] = A[r];
    __syncthreads();   // [barrier 3]
#pragma unroll
    for (int r = 0; r < 16; ++r) A[r] = sc[q2b ^ ((r << 8) ^ ((r & 3) << 3))];

    // ---- gates wires 3..0 (Q2 reg bit j <-> wire 3-j) ----
#pragma unroll
    for (int j = 0; j < 4; ++j) {
        const int q = 3 - j;
        float4 lo = *(const float4*)&fm[1][q][0], hi = *(const float4*)&fm[1][q][4];
        v2 u00 = {lo.x, lo.y}, u01 = {lo.z, lo.w}, u10 = {hi.x, hi.y}, u11 = {hi.z, hi.w};
#pragma unroll
        for (int r0 = 0; r0 < 16; ++r0) {
            if (r0 & (1 << j)) continue;
            gate2(A[r0], A[r0 | (1 << j)], u00, u01, u10, u11);
        }
    }

    // ---- epilogue: ring2 folded into sign masks. Q2: i=(r<<8)|(Wv<<6)|L.
    // sign_q(i) = par(i & T_m), m=11-q; T_m = bits m..11 (m<=10), T_11 = bits 0..10.
    float A7 = 0.f, AC = 0.f, AE = 0.f, AF = 0.f;
#pragma unroll
    for (int r = 0; r < 16; ++r) {
        float p = A[r].x * A[r].x + A[r].y * A[r].y;
        A7 += par12(r & 0x7) ? -p : p;
        AC += par12(r & 0xC) ? -p : p;
        AE += par12(r & 0xE) ? -p : p;
        AF += par12(r & 0xF) ? -p : p;
    }
    const int pWv = (Wv ^ (Wv >> 1)) & 1;
    const int pL  = __popc(L & 0x3F) & 1;
    float v[NQ];
    v[0] = (pL ^ pWv) ? -A7 : A7;          // m=11: par(L)^par(Wv)^par(r&7)
    v[1] = AC;                              // m=10: bits10,11 = r2,r3
    v[2] = AE;                              // m=9
    v[3] = AF;                              // m=8
    v[4] = (Wv >> 1) ? -AF : AF;            // m=7: Wv1 ^ par(r)
    v[5] = pWv ? -AF : AF;                  // m=6: par(Wv) ^ par(r)
#pragma unroll
    for (int q = 6; q < NQ; ++q) {          // m=5..0: par(L&ML)^par(Wv)^par(r)
        int m = 11 - q;
        int ML = 0x3F ^ ((1 << m) - 1);
        int s = pWv ^ (__popc(L & ML) & 1);
        v[q] = s ? -AF : AF;
    }

#pragma unroll
    for (int q = 0; q < NQ; ++q)
        for (int off = 32; off > 0; off >>= 1)
            v[q] += __shfl_xor(v[q], off, 64);

    if (L == 0) {
#pragma unroll
        for (int q = 0; q < NQ; ++q) red[Wv][q] = v[q];
    }
    __syncthreads();   // [barrier 4]
    if (t < NQ) out[b * NQ + t] = red[0][t] + red[1][t] + red[2][t] + red[3][t];
}

extern "C" void kernel_launch(void* const* d_in, const int* in_sizes, int n_in,
                              void* d_out, int out_size, void* d_ws, size_t ws_size,
                              hipStream_t stream) {
    int xi = 0, wi = 1;
    if (n_in >= 2 && in_sizes[1] > in_sizes[0]) { xi = 1; wi = 0; }
    const float* x = (const float*)d_in[xi];
    const float* w = (const float*)d_in[wi];
    float* out = (float*)d_out;
    const int B = in_sizes[xi] / NQ;   // 1024
    qsim_kernel<<<B, NT, 0, stream>>>(x, w, out);
}